// Round 1
// baseline (121.999 us; speedup 1.0000x reference)
//
#include <hip/hip_runtime.h>
#include <math.h>

#define IN_F 256
#define OUT_F 128
#define NHEAD 2
#define ALPHA 0.2f
#define NN 4096          // compile-time N (problem-fixed)
#define NCAP 128         // max neighbors/row (max degree ~45+1; 128 = 23 sigma)

typedef __attribute__((ext_vector_type(8))) short short8;
typedef __attribute__((ext_vector_type(4))) float f32x4;
typedef const __attribute__((address_space(1))) void* gas_ptr;
typedef __attribute__((address_space(3))) void* las_ptr;

__device__ __forceinline__ void async_copy16(const void* g, void* l) {
  __builtin_amdgcn_global_load_lds((gas_ptr)g, (las_ptr)l, 16, 0, 0);
}

__device__ __forceinline__ ushort f2bf(float f) {
  unsigned u = __float_as_uint(f);
  u += 0x7fffu + ((u >> 16) & 1u);  // RNE
  return (ushort)(u >> 16);
}

__device__ __forceinline__ float lrelu(float t) { return t > 0.f ? t : ALPHA * t; }

// ---------------------------------------------------------------------------
// prep_w: Wt[h][o][k] = bf16(W[h][k][o])  (transpose + cast; 64 blocks)
// ---------------------------------------------------------------------------
__global__ __launch_bounds__(256) void prep_w(
    const float* __restrict__ W, ushort* __restrict__ Wt) {
  int p = blockIdx.x * 256 + threadIdx.x;   // 16384 ushort4 outputs
  int h = p >> 13;
  int rem = p & 8191;
  int c = rem >> 7;       // k-quad 0..63
  int o = rem & 127;
  const float* wsrc = W + h * (IN_F * OUT_F) + (4 * c) * OUT_F + o;
  ushort4 ov;
  ov.x = f2bf(wsrc[0 * OUT_F]);
  ov.y = f2bf(wsrc[1 * OUT_F]);
  ov.z = f2bf(wsrc[2 * OUT_F]);
  ov.w = f2bf(wsrc[3 * OUT_F]);
  *(ushort4*)(Wt + ((size_t)h * OUT_F + o) * IN_F + 4 * c) = ov;
}

// ---------------------------------------------------------------------------
// gemm_scan: FUSED. Grid 1024 blocks x 256.
//  - blocks with (bid&3)==0 run one M32 GEMM tile (tile = bid>>2, 256 tiles)
//    with fused e1/e2 epilogue (R7-proven structure, unchanged).
//  - ALL blocks then run the adj ballot-compaction for rows bid*4+wave,
//    writing neighbor lists + counts to workspace. Compaction has no data
//    dependence on the GEMM, so the 64 MB adj HBM stream overlaps the
//    GEMM's staging-latency stalls instead of serializing after it.
// ---------------------------------------------------------------------------
__global__ __launch_bounds__(256) void gemm_scan(
    const float* __restrict__ x, const ushort* __restrict__ Wt,
    const float* __restrict__ a, const float* __restrict__ adj,
    float* __restrict__ xt, float* __restrict__ e1, float* __restrict__ e2,
    int* __restrict__ nbr, int* __restrict__ cnt) {
  __shared__ ushort sA[32 * 64];    //  4 KB
  __shared__ ushort sB[128 * 64];   // 16 KB
  __shared__ float sa[2 * OUT_F];
  __shared__ float se1[32], se2[32];
  __shared__ int s_nbr[4][NCAP];    //  2 KB

  const int bid = blockIdx.x;
  const int tid = threadIdx.x;
  const int wave = tid >> 6, lane = tid & 63;

  if ((bid & 3) == 0) {
    // ---------------- GEMM tile ----------------
    const int tile = bid >> 2;            // 0..255
    const int h = tile >> 7;              // 0..1
    const int rowBase = (tile & 127) * 32;
    const int wr = wave & 1, wc = wave >> 1;
    const int q = lane >> 4, l16 = lane & 15;
    const int ar = tid >> 3;              // A row 0..31
    const int ak = (tid & 7) * 8;         // A col-octet 0..56

    // A prefetch: full row-slice for all 4 chunks (8 float4s, independent)
    const float* xrow = x + (size_t)(rowBase + ar) * IN_F + ak;
    float4 ax[8];
#pragma unroll
    for (int c = 0; c < 4; ++c) {
      ax[2 * c]     = *(const float4*)(xrow + 64 * c);
      ax[2 * c + 1] = *(const float4*)(xrow + 64 * c + 4);
    }

    sa[tid] = a[h * (2 * OUT_F) + tid];

    f32x4 acc[4];
#pragma unroll
    for (int i = 0; i < 4; ++i) acc[i] = (f32x4)(0.0f);

    const char* wbase = (const char*)(Wt + (size_t)h * (OUT_F * IN_F));

#pragma unroll
    for (int c = 0; c < 4; ++c) {
      const int k0 = c * 64;
      // B tile: 128x64 bf16 = 1024 granules of 16B, 4/thread (async)
#pragma unroll
      for (int it = 0; it < 4; ++it) {
        int g = it * 256 + tid;
        int r = g >> 3, c8 = g & 7;
        async_copy16(wbase + r * 512 + k0 * 2 + c8 * 16,
                     (char*)sB + (size_t)(it * 256 + wave * 64) * 16);
      }
      // A tile: cast prefetched regs -> LDS
      {
        float4 va = ax[2 * c], vb = ax[2 * c + 1];
        union { short8 s8; ushort u[8]; } pk;
        pk.u[0] = f2bf(va.x); pk.u[1] = f2bf(va.y);
        pk.u[2] = f2bf(va.z); pk.u[3] = f2bf(va.w);
        pk.u[4] = f2bf(vb.x); pk.u[5] = f2bf(vb.y);
        pk.u[6] = f2bf(vb.z); pk.u[7] = f2bf(vb.w);
        *(short8*)(sA + ar * 64 + ak) = pk.s8;
      }
      __syncthreads();

#pragma unroll
      for (int ks = 0; ks < 64; ks += 32) {
        short8 af = *(const short8*)(sA + (wr * 16 + l16) * 64 + ks + q * 8);
#pragma unroll
        for (int ct = 0; ct < 4; ++ct) {
          int col = wc * 64 + ct * 16 + l16;
          short8 bf = *(const short8*)(sB + col * 64 + ks + q * 8);
          acc[ct] = __builtin_amdgcn_mfma_f32_16x16x32_bf16(af, bf, acc[ct], 0, 0, 0);
        }
      }
      __syncthreads();
    }

    // epilogue 1: store xt (D: row = q*4+reg, col = l16)
#pragma unroll
    for (int ct = 0; ct < 4; ++ct) {
      int col = wc * 64 + ct * 16 + l16;
#pragma unroll
      for (int reg = 0; reg < 4; ++reg) {
        int row = rowBase + wr * 16 + q * 4 + reg;
        xt[((size_t)h * NN + row) * OUT_F + col] = acc[ct][reg];
      }
    }

    // epilogue 2: fused e1/e2
    float pe1[4], pe2[4];
#pragma unroll
    for (int reg = 0; reg < 4; ++reg) { pe1[reg] = 0.f; pe2[reg] = 0.f; }
#pragma unroll
    for (int ct = 0; ct < 4; ++ct) {
      int col = wc * 64 + ct * 16 + l16;
      float a1v = sa[col], a2v = sa[OUT_F + col];
#pragma unroll
      for (int reg = 0; reg < 4; ++reg) {
        pe1[reg] = fmaf(acc[ct][reg], a1v, pe1[reg]);
        pe2[reg] = fmaf(acc[ct][reg], a2v, pe2[reg]);
      }
    }
#pragma unroll
    for (int off = 1; off < 16; off <<= 1) {
#pragma unroll
      for (int reg = 0; reg < 4; ++reg) {
        pe1[reg] += __shfl_xor(pe1[reg], off, 64);
        pe2[reg] += __shfl_xor(pe2[reg], off, 64);
      }
    }
    if (wc == 0 && l16 == 0) {
#pragma unroll
      for (int reg = 0; reg < 4; ++reg) {
        int r = wr * 16 + q * 4 + reg;
        se1[r] = pe1[reg];
        se2[r] = pe2[reg];
      }
    }
    __syncthreads();
    if (wc == 1 && l16 == 0) {
#pragma unroll
      for (int reg = 0; reg < 4; ++reg) {
        int r = wr * 16 + q * 4 + reg;
        se1[r] += pe1[reg];
        se2[r] += pe2[reg];
      }
    }
    __syncthreads();
    if (tid < 32) {
      e1[(size_t)h * NN + rowBase + tid] = se1[tid];
      e2[(size_t)h * NN + rowBase + tid] = se2[tid];
    }
  }

  // ---------------- adj scan / compaction (ALL blocks, wave-per-row) -------
  const int i = bid * 4 + wave;

  const float4* row4 = (const float4*)(adj + (size_t)i * NN);
  float4 v[16];
#pragma unroll
  for (int c = 0; c < 16; ++c) v[c] = row4[lane + c * 64];

  const unsigned long long lt = (1ull << lane) - 1ull;
  int total = 0;
#pragma unroll
  for (int c = 0; c < 16; ++c) {
    float vals[4] = {v[c].x, v[c].y, v[c].z, v[c].w};
#pragma unroll
    for (int s = 0; s < 4; ++s) {
      int j = (c * 64 + lane) * 4 + s;
      bool hit = (vals[s] > 0.f) || (j == i);
      unsigned long long mask = __ballot(hit);
      if (hit) {
        int pos = total + (int)__popcll(mask & lt);
        if (pos < NCAP) s_nbr[wave][pos] = j;
      }
      total += (int)__popcll(mask);
    }
  }
  const int m = total < NCAP ? total : NCAP;
#pragma unroll
  for (int r = 0; r < 2; ++r) {
    int k = lane + r * 64;
    if (k < m) nbr[(size_t)i * NCAP + k] = s_nbr[wave][k];
  }
  if (lane == 0) cnt[i] = m;
}

// ---------------------------------------------------------------------------
// gat_gather: wave-per-row, barrier-free, from precomputed neighbor lists.
// All inputs L2/LLC-resident (nbr 2 MB, xt 4 MB, e1/e2 64 KB); writes 4 MB.
// ---------------------------------------------------------------------------
__global__ __launch_bounds__(256) void gat_gather(
    const float* __restrict__ xt, const float* __restrict__ e1,
    const float* __restrict__ e2, const int* __restrict__ nbr,
    const int* __restrict__ cnt, float* __restrict__ out) {
  __shared__ int s_nbr[4][NCAP];
  __shared__ float s_p0[4][NCAP];
  __shared__ float s_p1[4][NCAP];

  const int wave = threadIdx.x >> 6;
  const int lane = threadIdx.x & 63;
  const int i = blockIdx.x * 4 + wave;   // this wave's row

  const int m = cnt[i];

  // ---- load neighbor list (coalesced), keep in regs + LDS ----
  int jr[2] = {0, 0};
#pragma unroll
  for (int r = 0; r < 2; ++r) {
    int k = lane + r * 64;
    if (k < m) {
      int j = nbr[(size_t)i * NCAP + k];
      jr[r] = j;
      s_nbr[wave][k] = j;
    }
  }

  // ---- scores in registers (k = lane, lane+64) ----
  const float e10 = e1[i];
  const float e11 = e1[NN + i];
  float t0[2], t1[2];
  float mx0 = -3.0e38f, mx1 = -3.0e38f;
#pragma unroll
  for (int r = 0; r < 2; ++r) {
    int k = lane + r * 64;
    if (k < m) {
      int j = jr[r];
      t0[r] = lrelu(e10 + e2[j]);
      t1[r] = lrelu(e11 + e2[NN + j]);
      mx0 = fmaxf(mx0, t0[r]);
      mx1 = fmaxf(mx1, t1[r]);
    } else {
      t0[r] = -3.0e38f;
      t1[r] = -3.0e38f;
    }
  }
#pragma unroll
  for (int off = 32; off > 0; off >>= 1) {
    mx0 = fmaxf(mx0, __shfl_xor(mx0, off, 64));
    mx1 = fmaxf(mx1, __shfl_xor(mx1, off, 64));
  }

  // ---- exp, write weights to LDS, wave-sum denominators ----
  float s0 = 0.f, s1 = 0.f;
#pragma unroll
  for (int r = 0; r < 2; ++r) {
    int k = lane + r * 64;
    if (k < m) {
      float p0 = __expf(t0[r] - mx0);
      float p1 = __expf(t1[r] - mx1);
      s_p0[wave][k] = p0;
      s_p1[wave][k] = p1;
      s0 += p0;
      s1 += p1;
    }
  }
#pragma unroll
  for (int off = 32; off > 0; off >>= 1) {
    s0 += __shfl_xor(s0, off, 64);
    s1 += __shfl_xor(s1, off, 64);
  }

  // ---- gather-accumulate (float4/lane), x4 unrolled ----
  const int h = lane >> 5;
  const int o4 = (lane & 31) * 4;
  const float linv = 1.0f / (h ? s1 : s0);
  const float* pw = h ? s_p1[wave] : s_p0[wave];
  const int* nb = s_nbr[wave];
  const float* xth = xt + (size_t)h * NN * OUT_F + o4;

  f32x4 acc = (f32x4)(0.0f);
  int k = 0;
  for (; k + 4 <= m; k += 4) {
    int j0 = nb[k], j1 = nb[k + 1], j2 = nb[k + 2], j3 = nb[k + 3];
    float w0 = pw[k], w1 = pw[k + 1], w2 = pw[k + 2], w3 = pw[k + 3];
    f32x4 x0 = *(const f32x4*)(xth + (size_t)j0 * OUT_F);
    f32x4 x1 = *(const f32x4*)(xth + (size_t)j1 * OUT_F);
    f32x4 x2 = *(const f32x4*)(xth + (size_t)j2 * OUT_F);
    f32x4 x3 = *(const f32x4*)(xth + (size_t)j3 * OUT_F);
    acc += w0 * x0;
    acc += w1 * x1;
    acc += w2 * x2;
    acc += w3 * x3;
  }
  for (; k < m; ++k) {
    f32x4 xv = *(const f32x4*)(xth + (size_t)nb[k] * OUT_F);
    acc += pw[k] * xv;
  }

  // ---- epilogue: normalize, ELU, float4 store ----
  f32x4 r;
#pragma unroll
  for (int e = 0; e < 4; ++e) {
    float av = acc[e] * linv;
    r[e] = av > 0.f ? av : (__expf(av) - 1.0f);
  }
  *(f32x4*)(out + ((size_t)h * NN + i) * OUT_F + o4) = r;
}

// ---------------------------------------------------------------------------
extern "C" void kernel_launch(void* const* d_in, const int* in_sizes, int n_in,
                              void* d_out, int out_size, void* d_ws, size_t ws_size,
                              hipStream_t stream) {
  const float* x   = (const float*)d_in[0];
  const float* adj = (const float*)d_in[1];
  const float* W   = (const float*)d_in[2];
  const float* a   = (const float*)d_in[3];
  float* out = (float*)d_out;

  float* xt = (float*)d_ws;                                  // H*N*OUT_F f32 (4 MB)
  float* e1 = xt + (size_t)NHEAD * NN * OUT_F;               // H*N
  float* e2 = e1 + (size_t)NHEAD * NN;                       // H*N
  ushort* Wt = (ushort*)(e2 + (size_t)NHEAD * NN);           // H*OUT_F*IN_F bf16 (128 KB)
  int* nbr = (int*)(Wt + (size_t)NHEAD * OUT_F * IN_F);      // N*NCAP int (2 MB)
  int* cnt = nbr + (size_t)NN * NCAP;                        // N int

  prep_w<<<64, 256, 0, stream>>>(W, Wt);
  gemm_scan<<<1024, 256, 0, stream>>>(x, Wt, a, adj, xt, e1, e2, nbr, cnt);
  gat_gather<<<NN / 4, 256, 0, stream>>>(xt, e1, e2, nbr, cnt, out);
}

// Round 2
// 114.182 us; speedup vs baseline: 1.0685x; 1.0685x over previous
//
#include <hip/hip_runtime.h>
#include <math.h>

#define IN_F 256
#define OUT_F 128
#define NHEAD 2
#define ALPHA 0.2f
#define NN 4096          // compile-time N (problem-fixed)
#define NCAP 128         // max neighbors/row (max degree ~45+1; 128 = 23 sigma)

typedef __attribute__((ext_vector_type(8))) short short8;
typedef __attribute__((ext_vector_type(4))) float f32x4;
typedef const __attribute__((address_space(1))) void* gas_ptr;
typedef __attribute__((address_space(3))) void* las_ptr;

__device__ __forceinline__ void async_copy16(const void* g, void* l) {
  __builtin_amdgcn_global_load_lds((gas_ptr)g, (las_ptr)l, 16, 0, 0);
}

__device__ __forceinline__ ushort f2bf(float f) {
  unsigned u = __float_as_uint(f);
  u += 0x7fffu + ((u >> 16) & 1u);  // RNE
  return (ushort)(u >> 16);
}

__device__ __forceinline__ float lrelu(float t) { return t > 0.f ? t : ALPHA * t; }

// ---------------------------------------------------------------------------
// prep_w: Wt[h][o][k] = bf16(W[h][k][o])  (transpose + cast; 64 blocks)
// ---------------------------------------------------------------------------
__global__ __launch_bounds__(256) void prep_w(
    const float* __restrict__ W, ushort* __restrict__ Wt) {
  int p = blockIdx.x * 256 + threadIdx.x;   // 16384 ushort4 outputs
  int h = p >> 13;
  int rem = p & 8191;
  int c = rem >> 7;       // k-quad 0..63
  int o = rem & 127;
  const float* wsrc = W + h * (IN_F * OUT_F) + (4 * c) * OUT_F + o;
  ushort4 ov;
  ov.x = f2bf(wsrc[0 * OUT_F]);
  ov.y = f2bf(wsrc[1 * OUT_F]);
  ov.z = f2bf(wsrc[2 * OUT_F]);
  ov.w = f2bf(wsrc[3 * OUT_F]);
  *(ushort4*)(Wt + ((size_t)h * OUT_F + o) * IN_F + 4 * c) = ov;
}

// ---------------------------------------------------------------------------
// gemm_scan: FUSED. Grid 1024 blocks x 256.
//  - blocks bid < 256 run one M32 GEMM tile (tile = bid) with fused e1/e2
//    epilogue. bid<256 spans bid%8 = 0..7 uniformly -> 32 GEMM blocks per
//    XCD, ~1 per CU, dispatched FIRST. (R1 bug: (bid&3)==0 put all GEMM
//    tiles on XCDs {0,4} -> 4x serialization. This is the fix.)
//  - ALL blocks then run the adj ballot-compaction for rows bid*4+wave.
//    The 64 MB adj HBM stream (768 scan-only blocks) overlaps the GEMM's
//    staging/latency stalls instead of serializing after it.
// ---------------------------------------------------------------------------
__global__ __launch_bounds__(256) void gemm_scan(
    const float* __restrict__ x, const ushort* __restrict__ Wt,
    const float* __restrict__ a, const float* __restrict__ adj,
    float* __restrict__ xt, float* __restrict__ e1, float* __restrict__ e2,
    int* __restrict__ nbr, int* __restrict__ cnt) {
  __shared__ ushort sA[32 * 64];    //  4 KB
  __shared__ ushort sB[128 * 64];   // 16 KB
  __shared__ float sa[2 * OUT_F];
  __shared__ float se1[32], se2[32];
  __shared__ int s_nbr[4][NCAP];    //  2 KB

  const int bid = blockIdx.x;
  const int tid = threadIdx.x;
  const int wave = tid >> 6, lane = tid & 63;

  if (bid < 256) {
    // ---------------- GEMM tile ----------------
    const int tile = bid;                 // 0..255
    const int h = tile >> 7;              // 0..1
    const int rowBase = (tile & 127) * 32;
    const int wr = wave & 1, wc = wave >> 1;
    const int q = lane >> 4, l16 = lane & 15;
    const int ar = tid >> 3;              // A row 0..31
    const int ak = (tid & 7) * 8;         // A col-octet 0..56

    // A prefetch: full row-slice for all 4 chunks (8 float4s, independent)
    const float* xrow = x + (size_t)(rowBase + ar) * IN_F + ak;
    float4 ax[8];
#pragma unroll
    for (int c = 0; c < 4; ++c) {
      ax[2 * c]     = *(const float4*)(xrow + 64 * c);
      ax[2 * c + 1] = *(const float4*)(xrow + 64 * c + 4);
    }

    sa[tid] = a[h * (2 * OUT_F) + tid];

    f32x4 acc[4];
#pragma unroll
    for (int i = 0; i < 4; ++i) acc[i] = (f32x4)(0.0f);

    const char* wbase = (const char*)(Wt + (size_t)h * (OUT_F * IN_F));

#pragma unroll
    for (int c = 0; c < 4; ++c) {
      const int k0 = c * 64;
      // B tile: 128x64 bf16 = 1024 granules of 16B, 4/thread (async)
#pragma unroll
      for (int it = 0; it < 4; ++it) {
        int g = it * 256 + tid;
        int r = g >> 3, c8 = g & 7;
        async_copy16(wbase + r * 512 + k0 * 2 + c8 * 16,
                     (char*)sB + (size_t)(it * 256 + wave * 64) * 16);
      }
      // A tile: cast prefetched regs -> LDS
      {
        float4 va = ax[2 * c], vb = ax[2 * c + 1];
        union { short8 s8; ushort u[8]; } pk;
        pk.u[0] = f2bf(va.x); pk.u[1] = f2bf(va.y);
        pk.u[2] = f2bf(va.z); pk.u[3] = f2bf(va.w);
        pk.u[4] = f2bf(vb.x); pk.u[5] = f2bf(vb.y);
        pk.u[6] = f2bf(vb.z); pk.u[7] = f2bf(vb.w);
        *(short8*)(sA + ar * 64 + ak) = pk.s8;
      }
      __syncthreads();

      // MFMA cluster: co-resident scan waves are flooding the memory pipe;
      // setprio biases the CU scheduler toward the matrix-phase waves
      // (role-split regime where T5 is measured-positive).
      __builtin_amdgcn_s_setprio(1);
#pragma unroll
      for (int ks = 0; ks < 64; ks += 32) {
        short8 af = *(const short8*)(sA + (wr * 16 + l16) * 64 + ks + q * 8);
#pragma unroll
        for (int ct = 0; ct < 4; ++ct) {
          int col = wc * 64 + ct * 16 + l16;
          short8 bf = *(const short8*)(sB + col * 64 + ks + q * 8);
          acc[ct] = __builtin_amdgcn_mfma_f32_16x16x32_bf16(af, bf, acc[ct], 0, 0, 0);
        }
      }
      __builtin_amdgcn_s_setprio(0);
      __syncthreads();
    }

    // epilogue 1: store xt (D: row = q*4+reg, col = l16)
#pragma unroll
    for (int ct = 0; ct < 4; ++ct) {
      int col = wc * 64 + ct * 16 + l16;
#pragma unroll
      for (int reg = 0; reg < 4; ++reg) {
        int row = rowBase + wr * 16 + q * 4 + reg;
        xt[((size_t)h * NN + row) * OUT_F + col] = acc[ct][reg];
      }
    }

    // epilogue 2: fused e1/e2
    float pe1[4], pe2[4];
#pragma unroll
    for (int reg = 0; reg < 4; ++reg) { pe1[reg] = 0.f; pe2[reg] = 0.f; }
#pragma unroll
    for (int ct = 0; ct < 4; ++ct) {
      int col = wc * 64 + ct * 16 + l16;
      float a1v = sa[col], a2v = sa[OUT_F + col];
#pragma unroll
      for (int reg = 0; reg < 4; ++reg) {
        pe1[reg] = fmaf(acc[ct][reg], a1v, pe1[reg]);
        pe2[reg] = fmaf(acc[ct][reg], a2v, pe2[reg]);
      }
    }
#pragma unroll
    for (int off = 1; off < 16; off <<= 1) {
#pragma unroll
      for (int reg = 0; reg < 4; ++reg) {
        pe1[reg] += __shfl_xor(pe1[reg], off, 64);
        pe2[reg] += __shfl_xor(pe2[reg], off, 64);
      }
    }
    if (wc == 0 && l16 == 0) {
#pragma unroll
      for (int reg = 0; reg < 4; ++reg) {
        int r = wr * 16 + q * 4 + reg;
        se1[r] = pe1[reg];
        se2[r] = pe2[reg];
      }
    }
    __syncthreads();
    if (wc == 1 && l16 == 0) {
#pragma unroll
      for (int reg = 0; reg < 4; ++reg) {
        int r = wr * 16 + q * 4 + reg;
        se1[r] += pe1[reg];
        se2[r] += pe2[reg];
      }
    }
    __syncthreads();
    if (tid < 32) {
      e1[(size_t)h * NN + rowBase + tid] = se1[tid];
      e2[(size_t)h * NN + rowBase + tid] = se2[tid];
    }
  }

  // ---------------- adj scan / compaction (ALL blocks, wave-per-row) -------
  const int i = bid * 4 + wave;

  const float4* row4 = (const float4*)(adj + (size_t)i * NN);
  float4 v[16];
#pragma unroll
  for (int c = 0; c < 16; ++c) v[c] = row4[lane + c * 64];

  const unsigned long long lt = (1ull << lane) - 1ull;
  int total = 0;
#pragma unroll
  for (int c = 0; c < 16; ++c) {
    float vals[4] = {v[c].x, v[c].y, v[c].z, v[c].w};
#pragma unroll
    for (int s = 0; s < 4; ++s) {
      int j = (c * 64 + lane) * 4 + s;
      bool hit = (vals[s] > 0.f) || (j == i);
      unsigned long long mask = __ballot(hit);
      if (hit) {
        int pos = total + (int)__popcll(mask & lt);
        if (pos < NCAP) s_nbr[wave][pos] = j;
      }
      total += (int)__popcll(mask);
    }
  }
  const int m = total < NCAP ? total : NCAP;
#pragma unroll
  for (int r = 0; r < 2; ++r) {
    int k = lane + r * 64;
    if (k < m) nbr[(size_t)i * NCAP + k] = s_nbr[wave][k];
  }
  if (lane == 0) cnt[i] = m;
}

// ---------------------------------------------------------------------------
// gat_gather: wave-per-row, barrier-free, from precomputed neighbor lists.
// All inputs L2/LLC-resident (nbr 2 MB, xt 4 MB, e1/e2 64 KB); writes 4 MB.
// ---------------------------------------------------------------------------
__global__ __launch_bounds__(256) void gat_gather(
    const float* __restrict__ xt, const float* __restrict__ e1,
    const float* __restrict__ e2, const int* __restrict__ nbr,
    const int* __restrict__ cnt, float* __restrict__ out) {
  __shared__ int s_nbr[4][NCAP];
  __shared__ float s_p0[4][NCAP];
  __shared__ float s_p1[4][NCAP];

  const int wave = threadIdx.x >> 6;
  const int lane = threadIdx.x & 63;
  const int i = blockIdx.x * 4 + wave;   // this wave's row

  const int m = cnt[i];

  // ---- load neighbor list (coalesced), keep in regs + LDS ----
  int jr[2] = {0, 0};
#pragma unroll
  for (int r = 0; r < 2; ++r) {
    int k = lane + r * 64;
    if (k < m) {
      int j = nbr[(size_t)i * NCAP + k];
      jr[r] = j;
      s_nbr[wave][k] = j;
    }
  }

  // ---- scores in registers (k = lane, lane+64) ----
  const float e10 = e1[i];
  const float e11 = e1[NN + i];
  float t0[2], t1[2];
  float mx0 = -3.0e38f, mx1 = -3.0e38f;
#pragma unroll
  for (int r = 0; r < 2; ++r) {
    int k = lane + r * 64;
    if (k < m) {
      int j = jr[r];
      t0[r] = lrelu(e10 + e2[j]);
      t1[r] = lrelu(e11 + e2[NN + j]);
      mx0 = fmaxf(mx0, t0[r]);
      mx1 = fmaxf(mx1, t1[r]);
    } else {
      t0[r] = -3.0e38f;
      t1[r] = -3.0e38f;
    }
  }
#pragma unroll
  for (int off = 32; off > 0; off >>= 1) {
    mx0 = fmaxf(mx0, __shfl_xor(mx0, off, 64));
    mx1 = fmaxf(mx1, __shfl_xor(mx1, off, 64));
  }

  // ---- exp, write weights to LDS, wave-sum denominators ----
  float s0 = 0.f, s1 = 0.f;
#pragma unroll
  for (int r = 0; r < 2; ++r) {
    int k = lane + r * 64;
    if (k < m) {
      float p0 = __expf(t0[r] - mx0);
      float p1 = __expf(t1[r] - mx1);
      s_p0[wave][k] = p0;
      s_p1[wave][k] = p1;
      s0 += p0;
      s1 += p1;
    }
  }
#pragma unroll
  for (int off = 32; off > 0; off >>= 1) {
    s0 += __shfl_xor(s0, off, 64);
    s1 += __shfl_xor(s1, off, 64);
  }

  // ---- gather-accumulate (float4/lane), x4 unrolled ----
  const int h = lane >> 5;
  const int o4 = (lane & 31) * 4;
  const float linv = 1.0f / (h ? s1 : s0);
  const float* pw = h ? s_p1[wave] : s_p0[wave];
  const int* nb = s_nbr[wave];
  const float* xth = xt + (size_t)h * NN * OUT_F + o4;

  f32x4 acc = (f32x4)(0.0f);
  int k = 0;
  for (; k + 4 <= m; k += 4) {
    int j0 = nb[k], j1 = nb[k + 1], j2 = nb[k + 2], j3 = nb[k + 3];
    float w0 = pw[k], w1 = pw[k + 1], w2 = pw[k + 2], w3 = pw[k + 3];
    f32x4 x0 = *(const f32x4*)(xth + (size_t)j0 * OUT_F);
    f32x4 x1 = *(const f32x4*)(xth + (size_t)j1 * OUT_F);
    f32x4 x2 = *(const f32x4*)(xth + (size_t)j2 * OUT_F);
    f32x4 x3 = *(const f32x4*)(xth + (size_t)j3 * OUT_F);
    acc += w0 * x0;
    acc += w1 * x1;
    acc += w2 * x2;
    acc += w3 * x3;
  }
  for (; k < m; ++k) {
    f32x4 xv = *(const f32x4*)(xth + (size_t)nb[k] * OUT_F);
    acc += pw[k] * xv;
  }

  // ---- epilogue: normalize, ELU, float4 store ----
  f32x4 r;
#pragma unroll
  for (int e = 0; e < 4; ++e) {
    float av = acc[e] * linv;
    r[e] = av > 0.f ? av : (__expf(av) - 1.0f);
  }
  *(f32x4*)(out + ((size_t)h * NN + i) * OUT_F + o4) = r;
}

// ---------------------------------------------------------------------------
extern "C" void kernel_launch(void* const* d_in, const int* in_sizes, int n_in,
                              void* d_out, int out_size, void* d_ws, size_t ws_size,
                              hipStream_t stream) {
  const float* x   = (const float*)d_in[0];
  const float* adj = (const float*)d_in[1];
  const float* W   = (const float*)d_in[2];
  const float* a   = (const float*)d_in[3];
  float* out = (float*)d_out;

  float* xt = (float*)d_ws;                                  // H*N*OUT_F f32 (4 MB)
  float* e1 = xt + (size_t)NHEAD * NN * OUT_F;               // H*N
  float* e2 = e1 + (size_t)NHEAD * NN;                       // H*N
  ushort* Wt = (ushort*)(e2 + (size_t)NHEAD * NN);           // H*OUT_F*IN_F bf16 (128 KB)
  int* nbr = (int*)(Wt + (size_t)NHEAD * OUT_F * IN_F);      // N*NCAP int (2 MB)
  int* cnt = nbr + (size_t)NN * NCAP;                        // N int

  prep_w<<<64, 256, 0, stream>>>(W, Wt);
  gemm_scan<<<1024, 256, 0, stream>>>(x, Wt, a, adj, xt, e1, e2, nbr, cnt);
  gat_gather<<<NN / 4, 256, 0, stream>>>(xt, e1, e2, nbr, cnt, out);
}

// Round 3
// 112.240 us; speedup vs baseline: 1.0869x; 1.0173x over previous
//
#include <hip/hip_runtime.h>
#include <math.h>

#define IN_F 256
#define OUT_F 128
#define NHEAD 2
#define ALPHA 0.2f
#define NN 4096          // compile-time N (problem-fixed)
#define NCAP 128         // max neighbors/row (max degree ~45+1; 128 = 23 sigma)

typedef __attribute__((ext_vector_type(8))) short short8;
typedef __attribute__((ext_vector_type(4))) float f32x4;
typedef const __attribute__((address_space(1))) void* gas_ptr;
typedef __attribute__((address_space(3))) void* las_ptr;

__device__ __forceinline__ void async_copy16(const void* g, void* l) {
  __builtin_amdgcn_global_load_lds((gas_ptr)g, (las_ptr)l, 16, 0, 0);
}

__device__ __forceinline__ ushort f2bf(float f) {
  unsigned u = __float_as_uint(f);
  u += 0x7fffu + ((u >> 16) & 1u);  // RNE
  return (ushort)(u >> 16);
}

__device__ __forceinline__ float lrelu(float t) { return t > 0.f ? t : ALPHA * t; }

// ---------------------------------------------------------------------------
// prep_w: Wt[h][o][k] = bf16(W[h][k][o])  (transpose + cast; 64 blocks)
// Layout is PLAIN row-major [o][k]; the GEMM pre-swizzles its staging SOURCE.
// ---------------------------------------------------------------------------
__global__ __launch_bounds__(256) void prep_w(
    const float* __restrict__ W, ushort* __restrict__ Wt) {
  int p = blockIdx.x * 256 + threadIdx.x;   // 16384 ushort4 outputs
  int h = p >> 13;
  int rem = p & 8191;
  int c = rem >> 7;       // k-quad 0..63
  int o = rem & 127;
  const float* wsrc = W + h * (IN_F * OUT_F) + (4 * c) * OUT_F + o;
  ushort4 ov;
  ov.x = f2bf(wsrc[0 * OUT_F]);
  ov.y = f2bf(wsrc[1 * OUT_F]);
  ov.z = f2bf(wsrc[2 * OUT_F]);
  ov.w = f2bf(wsrc[3 * OUT_F]);
  *(ushort4*)(Wt + ((size_t)h * OUT_F + o) * IN_F + 4 * c) = ov;
}

// ---------------------------------------------------------------------------
// gemm_mfma v3: M32 tile, grid (128, 2) = 256 blocks (1/CU).
//  - WHOLE-K staging: sB 128x256 bf16 (64 KB) + sA 32x256 (16 KB) in ONE
//    async volley (16 global_load_lds/thread) -> ONE __syncthreads ->
//    uninterrupted K=256 MFMA loop. Removes 6 barriers + 3 vmcnt(0) drains
//    vs the 4-chunk version.
//  - T2 XOR swizzle (granule ^= row&7, i.e. ushort idx ^= (row&7)<<3):
//    fragment reads were 16-way bank-conflicted (row stride 128B/512B,
//    lanes 0-15 same bank -- the m201 pattern). sB: linear LDS dest
//    (global_load_lds requirement) + inverse-swizzled GLOBAL source
//    (permutation stays inside each 128B line -> coalescing preserved);
//    sA: swizzled ds_write. Reads apply the same XOR. 16-way -> 2-way (free).
// ---------------------------------------------------------------------------
__global__ __launch_bounds__(256) void gemm_mfma(
    const float* __restrict__ x, const ushort* __restrict__ Wt,
    const float* __restrict__ a,
    float* __restrict__ xt, float* __restrict__ e1, float* __restrict__ e2) {
  __shared__ ushort sA[32 * 256];    // 16 KB, swizzled
  __shared__ ushort sB[128 * 256];   // 64 KB, swizzled
  __shared__ float sa[2 * OUT_F];
  __shared__ float se1[32], se2[32];

  const int h = blockIdx.y;
  const int rowBase = blockIdx.x * 32;
  const int tid = threadIdx.x;
  const int wave = tid >> 6, lane = tid & 63;
  const int wr = wave & 1, wc = wave >> 1;
  const int q = lane >> 4, l16 = lane & 15;
  const int ar = tid >> 3;          // A row 0..31
  const int ak = (tid & 7) * 8;     // A col-octet 0..56

  // ---- B: 4096 granules of 16 B, 16/thread, single volley ----
  // LDS granule g holds source granule (g&31)^(r&7) of row r=g>>5; the
  // read-side XOR undoes it. LDS dest = wave-uniform base + lane*16.
  const char* wbase = (const char*)(Wt + (size_t)h * (OUT_F * IN_F));
#pragma unroll
  for (int it = 0; it < 16; ++it) {
    int g = it * 256 + tid;
    int r = g >> 5, c32 = g & 31;
    async_copy16(wbase + r * 512 + ((c32 ^ (r & 7)) * 16),
                 (char*)sB + (size_t)(it * 256 + wave * 64) * 16);
  }

  // ---- A: 8 independent float4 loads (overlap B's global latency) ----
  const float* xrow = x + (size_t)(rowBase + ar) * IN_F + ak;
  float4 ax[8];
#pragma unroll
  for (int c = 0; c < 4; ++c) {
    ax[2 * c]     = *(const float4*)(xrow + 64 * c);
    ax[2 * c + 1] = *(const float4*)(xrow + 64 * c + 4);
  }
#pragma unroll
  for (int c = 0; c < 4; ++c) {
    float4 va = ax[2 * c], vb = ax[2 * c + 1];
    union { short8 s8; ushort u[8]; } pk;
    pk.u[0] = f2bf(va.x); pk.u[1] = f2bf(va.y);
    pk.u[2] = f2bf(va.z); pk.u[3] = f2bf(va.w);
    pk.u[4] = f2bf(vb.x); pk.u[5] = f2bf(vb.y);
    pk.u[6] = f2bf(vb.z); pk.u[7] = f2bf(vb.w);
    *(short8*)(sA + ar * 256 + ((ak + 64 * c) ^ ((ar & 7) << 3))) = pk.s8;
  }

  sa[tid] = a[h * (2 * OUT_F) + tid];

  f32x4 acc[4];
#pragma unroll
  for (int i = 0; i < 4; ++i) acc[i] = (f32x4)(0.0f);

  __syncthreads();   // single drain: vmcnt(0)+lgkmcnt(0)+barrier

  // ---- K=256 MFMA loop, no barriers, swizzled conflict-free reads ----
  const int arow = wr * 16 + l16;
  const int aswz = (arow & 7) << 3;
#pragma unroll
  for (int ks = 0; ks < 256; ks += 32) {
    short8 af = *(const short8*)(sA + arow * 256 + ((ks + q * 8) ^ aswz));
#pragma unroll
    for (int ct = 0; ct < 4; ++ct) {
      int col = wc * 64 + ct * 16 + l16;
      short8 bf = *(const short8*)(sB + col * 256 + ((ks + q * 8) ^ ((col & 7) << 3)));
      acc[ct] = __builtin_amdgcn_mfma_f32_16x16x32_bf16(af, bf, acc[ct], 0, 0, 0);
    }
  }

  // epilogue 1: store xt (D: row = q*4+reg, col = l16)
#pragma unroll
  for (int ct = 0; ct < 4; ++ct) {
    int col = wc * 64 + ct * 16 + l16;
#pragma unroll
    for (int reg = 0; reg < 4; ++reg) {
      int row = rowBase + wr * 16 + q * 4 + reg;
      xt[((size_t)h * NN + row) * OUT_F + col] = acc[ct][reg];
    }
  }

  // epilogue 2: fused e1/e2
  float pe1[4], pe2[4];
#pragma unroll
  for (int reg = 0; reg < 4; ++reg) { pe1[reg] = 0.f; pe2[reg] = 0.f; }
#pragma unroll
  for (int ct = 0; ct < 4; ++ct) {
    int col = wc * 64 + ct * 16 + l16;
    float a1v = sa[col], a2v = sa[OUT_F + col];
#pragma unroll
    for (int reg = 0; reg < 4; ++reg) {
      pe1[reg] = fmaf(acc[ct][reg], a1v, pe1[reg]);
      pe2[reg] = fmaf(acc[ct][reg], a2v, pe2[reg]);
    }
  }
#pragma unroll
  for (int off = 1; off < 16; off <<= 1) {
#pragma unroll
    for (int reg = 0; reg < 4; ++reg) {
      pe1[reg] += __shfl_xor(pe1[reg], off, 64);
      pe2[reg] += __shfl_xor(pe2[reg], off, 64);
    }
  }
  if (wc == 0 && l16 == 0) {
#pragma unroll
    for (int reg = 0; reg < 4; ++reg) {
      int r = wr * 16 + q * 4 + reg;
      se1[r] = pe1[reg];
      se2[r] = pe2[reg];
    }
  }
  __syncthreads();
  if (wc == 1 && l16 == 0) {
#pragma unroll
    for (int reg = 0; reg < 4; ++reg) {
      int r = wr * 16 + q * 4 + reg;
      se1[r] += pe1[reg];
      se2[r] += pe2[reg];
    }
  }
  __syncthreads();
  if (tid < 32) {
    e1[(size_t)h * NN + rowBase + tid] = se1[tid];
    e2[(size_t)h * NN + rowBase + tid] = se2[tid];
  }
}

// ---------------------------------------------------------------------------
// gat_aggregate (R0-proven): WAVE-per-row, barrier-free. 4 rows/block,
// grid 1024. Ballot compaction, register softmax, float4 gather.
// Scan of later blocks naturally overlaps gather of earlier blocks.
// ---------------------------------------------------------------------------
__global__ __launch_bounds__(256) void gat_aggregate(
    const float* __restrict__ adj, const float* __restrict__ xt,
    const float* __restrict__ e1, const float* __restrict__ e2,
    float* __restrict__ out) {
  __shared__ int s_nbr[4][NCAP];
  __shared__ float s_p0[4][NCAP];
  __shared__ float s_p1[4][NCAP];

  const int wave = threadIdx.x >> 6;
  const int lane = threadIdx.x & 63;
  const int i = blockIdx.x * 4 + wave;   // this wave's row

  // ---- phase 1: scan row (16 float4/lane, all hoisted/in flight) ----
  const float4* row4 = (const float4*)(adj + (size_t)i * NN);
  float4 v[16];
#pragma unroll
  for (int c = 0; c < 16; ++c) v[c] = row4[lane + c * 64];

  const unsigned long long lt = (1ull << lane) - 1ull;
  int cnt = 0;
#pragma unroll
  for (int c = 0; c < 16; ++c) {
    float vals[4] = {v[c].x, v[c].y, v[c].z, v[c].w};
#pragma unroll
    for (int s = 0; s < 4; ++s) {
      int j = (c * 64 + lane) * 4 + s;
      bool hit = (vals[s] > 0.f) || (j == i);
      unsigned long long mask = __ballot(hit);
      if (hit) {
        int pos = cnt + (int)__popcll(mask & lt);
        if (pos < NCAP) s_nbr[wave][pos] = j;
      }
      cnt += (int)__popcll(mask);
    }
  }
  const int m = cnt < NCAP ? cnt : NCAP;

  // ---- phase 2: scores in registers (k = lane, lane+64) ----
  const float e10 = e1[i];
  const float e11 = e1[NN + i];
  float t0[2], t1[2];
  float mx0 = -3.0e38f, mx1 = -3.0e38f;
#pragma unroll
  for (int r = 0; r < 2; ++r) {
    int k = lane + r * 64;
    if (k < m) {
      int j = s_nbr[wave][k];
      t0[r] = lrelu(e10 + e2[j]);
      t1[r] = lrelu(e11 + e2[NN + j]);
      mx0 = fmaxf(mx0, t0[r]);
      mx1 = fmaxf(mx1, t1[r]);
    } else {
      t0[r] = -3.0e38f;
      t1[r] = -3.0e38f;
    }
  }
#pragma unroll
  for (int off = 32; off > 0; off >>= 1) {
    mx0 = fmaxf(mx0, __shfl_xor(mx0, off, 64));
    mx1 = fmaxf(mx1, __shfl_xor(mx1, off, 64));
  }

  // ---- phase 3: exp, write weights to LDS, wave-sum denominators ----
  float s0 = 0.f, s1 = 0.f;
#pragma unroll
  for (int r = 0; r < 2; ++r) {
    int k = lane + r * 64;
    if (k < m) {
      float p0 = __expf(t0[r] - mx0);
      float p1 = __expf(t1[r] - mx1);
      s_p0[wave][k] = p0;
      s_p1[wave][k] = p1;
      s0 += p0;
      s1 += p1;
    }
  }
#pragma unroll
  for (int off = 32; off > 0; off >>= 1) {
    s0 += __shfl_xor(s0, off, 64);
    s1 += __shfl_xor(s1, off, 64);
  }

  // ---- phase 4: gather-accumulate (float4/lane), x4 unrolled ----
  const int h = lane >> 5;
  const int o4 = (lane & 31) * 4;
  const float linv = 1.0f / (h ? s1 : s0);
  const float* pw = h ? s_p1[wave] : s_p0[wave];
  const int* nb = s_nbr[wave];
  const float* xth = xt + (size_t)h * NN * OUT_F + o4;

  f32x4 acc = (f32x4)(0.0f);
  int k = 0;
  for (; k + 4 <= m; k += 4) {
    int j0 = nb[k], j1 = nb[k + 1], j2 = nb[k + 2], j3 = nb[k + 3];
    float w0 = pw[k], w1 = pw[k + 1], w2 = pw[k + 2], w3 = pw[k + 3];
    f32x4 x0 = *(const f32x4*)(xth + (size_t)j0 * OUT_F);
    f32x4 x1 = *(const f32x4*)(xth + (size_t)j1 * OUT_F);
    f32x4 x2 = *(const f32x4*)(xth + (size_t)j2 * OUT_F);
    f32x4 x3 = *(const f32x4*)(xth + (size_t)j3 * OUT_F);
    acc += w0 * x0;
    acc += w1 * x1;
    acc += w2 * x2;
    acc += w3 * x3;
  }
  for (; k < m; ++k) {
    f32x4 xv = *(const f32x4*)(xth + (size_t)nb[k] * OUT_F);
    acc += pw[k] * xv;
  }

  // ---- epilogue: normalize, ELU, float4 store ----
  f32x4 r;
#pragma unroll
  for (int e = 0; e < 4; ++e) {
    float av = acc[e] * linv;
    r[e] = av > 0.f ? av : (__expf(av) - 1.0f);
  }
  *(f32x4*)(out + ((size_t)h * NN + i) * OUT_F + o4) = r;
}

// ---------------------------------------------------------------------------
extern "C" void kernel_launch(void* const* d_in, const int* in_sizes, int n_in,
                              void* d_out, int out_size, void* d_ws, size_t ws_size,
                              hipStream_t stream) {
  const float* x   = (const float*)d_in[0];
  const float* adj = (const float*)d_in[1];
  const float* W   = (const float*)d_in[2];
  const float* a   = (const float*)d_in[3];
  float* out = (float*)d_out;

  float* xt = (float*)d_ws;                                  // H*N*OUT_F f32 (4 MB)
  float* e1 = xt + (size_t)NHEAD * NN * OUT_F;               // H*N
  float* e2 = e1 + (size_t)NHEAD * NN;                       // H*N
  ushort* Wt = (ushort*)(e2 + (size_t)NHEAD * NN);           // H*OUT_F*IN_F bf16 (128 KB)

  prep_w<<<64, 256, 0, stream>>>(W, Wt);
  gemm_mfma<<<dim3(NN / 32, NHEAD), 256, 0, stream>>>(x, Wt, a, xt, e1, e2);
  gat_aggregate<<<NN / 4, 256, 0, stream>>>(adj, xt, e1, e2, out);
}